// Round 12
// baseline (377.012 us; speedup 1.0000x reference)
//
#include <hip/hip_runtime.h>
#include <stdint.h>

#define NM 16
#define HW_P 589824            // 768*768 pixels per mask
#define U8PM 9216              // u64 words per mask
#define F4PM 147456            // float4s per mask
#define F4PT 2359296           // float4s per tensor
#define NWG 72                 // single-wave WGs; 72*64 lanes*2 u64 = 9216 u64
#define SLOT0 864              // u64 offset of step slots (after 72*12 init)
#define SLOTB 154368           // slot region bytes = (864 + 64*72*4) * 8

typedef unsigned long long u64;
typedef float vf4 __attribute__((ext_vector_type(4)));

__device__ __forceinline__ u64 aload64(const u64* p) {
    return __hip_atomic_load(p, __ATOMIC_RELAXED, __HIP_MEMORY_SCOPE_AGENT);
}
__device__ __forceinline__ void astore64(u64* p, u64 v) {
    __hip_atomic_store(p, v, __ATOMIC_RELAXED, __HIP_MEMORY_SCOPE_AGENT);
}

__device__ __forceinline__ uint32_t spread4(uint32_t x) {
    uint32_t t = (x | (x << 12)) & 0x000F000Fu;
    t = (t | (t << 6)) & 0x03030303u;
    t = (t | (t << 3)) & 0x11111111u;
    return t;
}

// ---------------- kernel 1: binarize (coalesced) + slot zero ---------------
__global__ __launch_bounds__(256) void binarize_kernel(
    const float* __restrict__ ma, const float* __restrict__ mb,
    uint32_t* __restrict__ bitsA, uint32_t* __restrict__ bitsB,
    uint4* __restrict__ slots4)
{
    if (blockIdx.x < 38) {          // zero slot region (ws poisoned 0xAA and
        int idx = blockIdx.x * 256 + threadIdx.x;   // poison has bit63 set!)
        if (idx < SLOTB / 16) { uint4 z = {0u,0u,0u,0u}; slots4[idx] = z; }
    }
    int g = blockIdx.x * 256 + threadIdx.x;        // float4 index
    int tensor = (g >= F4PT);                      // %64==0: wave-uniform
    int lg = tensor ? (g - F4PT) : g;
    const float* src = tensor ? mb : ma;
    vf4 v = __builtin_nontemporal_load(((const vf4*)src) + lg);
    u64 q0 = __ballot(v.x > 0.0f);
    u64 q1 = __ballot(v.y > 0.0f);
    u64 q2 = __ballot(v.z > 0.0f);
    u64 q3 = __ballot(v.w > 0.0f);
    int lane = threadIdx.x & 63;
    if (lane < 8) {
        uint32_t wd = spread4((uint32_t)(q0 >> (8 * lane)) & 0xFFu)
                    | (spread4((uint32_t)(q1 >> (8 * lane)) & 0xFFu) << 1)
                    | (spread4((uint32_t)(q2 >> (8 * lane)) & 0xFFu) << 2)
                    | (spread4((uint32_t)(q3 >> (8 * lane)) & 0xFFu) << 3);
        uint32_t* bits = tensor ? bitsB : bitsA;
        bits[((lg & ~63) >> 3) + lane] = wd;       // word = 8 float4s
    }
}

// ---------------- kernel 2: bit-slice all-reduce filter --------------------
// 72 single-wave WGs; lane owns u64s {wg*128+lane, +64} of EVERY mask. All 32
// masks live in registers (B) / LDS (A) for the whole kernel — no mask bytes
// move between WGs. 64 super-steps (2x2 pair tiles, a valid linear extension
// of the reference (i,j) wavefront order); per step each WG posts 3
// self-sentineled u64s (9 basis popcounts, 16b fields) via relaxed agent
// atomics, polls all 72, sums, and replicates identical decisions.
__global__ __launch_bounds__(64, 1) void filter_kernel(
    const float* __restrict__ sa, const float* __restrict__ sb,
    uint32_t* bitsA, uint32_t* bitsB, int* meta, u64* slots)
{
    const int wg = blockIdx.x;
    const int lane = threadIdx.x;
    u64* A8 = (u64*)bitsA;
    u64* B8 = (u64*)bitsB;
    const size_t base = (size_t)wg * 128 + lane;

    __shared__ u64 ALds[16][128];
    __shared__ int s_pcA[16];

    // ---- load slices; A -> LDS, B -> registers; init popcount pack ----
    u64 pk[11];
#pragma unroll
    for (int i = 0; i < 11; ++i) pk[i] = 0;
    for (int m = 0; m < 16; ++m) {          // A (dynamic loop; LDS dest)
        u64 x0 = A8[(size_t)m * U8PM + base];
        u64 x1 = A8[(size_t)m * U8PM + base + 64];
        ALds[m][lane] = x0; ALds[m][64 + lane] = x1;
        int c = __popcll(x0) + __popcll(x1);
        pk[m / 3] += (u64)c << ((m % 3) * 16);
    }
    u64 B[16][2];
#pragma unroll
    for (int m = 0; m < 16; ++m) {          // B (static; registers)
        B[m][0] = B8[(size_t)m * U8PM + base];
        B[m][1] = B8[(size_t)m * U8PM + base + 64];
        int c = __popcll(B[m][0]) + __popcll(B[m][1]);
        int mm = 16 + m;
        pk[mm / 3] += (u64)c << ((mm % 3) * 16);
    }
#pragma unroll
    for (int off = 32; off >= 1; off >>= 1)
#pragma unroll
        for (int i = 0; i < 11; ++i) pk[i] += __shfl_xor(pk[i], off);

    // post init slot (11 u64, 3x16b fields + sentinel each)
    u64* myinit = slots + (size_t)wg * 12;
    if (lane == 0) {
#pragma unroll
        for (int i = 0; i < 11; ++i) astore64(&myinit[i], pk[i] | (1ull << 63));
    }
    asm volatile("" ::: "memory");
    // gather all 72 init slots: lane -> slot lane; lanes 0..7 also 64+lane
    int pcw[32];
    {
        u64 v[11], v2[11];
        const u64* s1 = slots + (size_t)lane * 12;
        const u64* s2 = slots + (size_t)(64 + lane) * 12;
        const bool two = (lane < 8);
        bool okall;
        do {
            bool ok = true;
#pragma unroll
            for (int i = 0; i < 11; ++i) { v[i] = aload64(&s1[i]); ok &= (v[i] >> 63) != 0; }
            if (two) {
#pragma unroll
                for (int i = 0; i < 11; ++i) { v2[i] = aload64(&s2[i]); ok &= (v2[i] >> 63) != 0; }
            }
            okall = __all(ok);
        } while (!okall);
#pragma unroll
        for (int m = 0; m < 32; ++m) {
            int f = (int)((v[m / 3] >> ((m % 3) * 16)) & 0xFFFF);
            if (two) f += (int)((v2[m / 3] >> ((m % 3) * 16)) & 0xFFFF);
            pcw[m] = f;
        }
        u64 q[11];
#pragma unroll
        for (int i = 0; i < 11; ++i) q[i] = 0;
#pragma unroll
        for (int m = 0; m < 32; ++m) q[m / 3] += (u64)pcw[m] << ((m % 3) * 21);
#pragma unroll
        for (int off = 32; off >= 1; off >>= 1)
#pragma unroll
            for (int i = 0; i < 11; ++i) q[i] += __shfl_xor(q[i], off);
#pragma unroll
        for (int m = 0; m < 32; ++m)
            pcw[m] = (int)((q[m / 3] >> ((m % 3) * 21)) & 0x1FFFFF);
    }
    if (lane == 0) {
#pragma unroll
        for (int m = 0; m < 16; ++m) s_pcA[m] = pcw[m];
    }
    __syncthreads();

    int pcb[16];
    float sBr[16];
#pragma unroll
    for (int j = 0; j < 16; ++j) { pcb[j] = pcw[16 + j]; sBr[j] = sb[j]; }
    unsigned faM = 0, fbM = 0;

    // ================= 64 super-steps: 8 row-tiles x 8 col-tiles ==========
    for (int rt = 0; rt < 8; ++rt) {
        const int i0 = 2 * rt, i1 = i0 + 1;
        u64 a0[2], a1[2];
        a0[0] = ALds[i0][lane]; a0[1] = ALds[i0][64 + lane];
        a1[0] = ALds[i1][lane]; a1[1] = ALds[i1][64 + lane];
        int pca0 = s_pcA[i0], pca1 = s_pcA[i1];
        int fa0 = 0, fa1 = 0;
        float sa0 = sa[i0], sa1 = sa[i1];

#pragma unroll
        for (int ct = 0; ct < 8; ++ct) {
            const int j0 = 2 * ct, j1 = j0 + 1;
            const int k = rt * 8 + ct;
            // ---- 9 basis popcounts from pre-tile states ----
            int t9[9];
            {
                int s0=0,s1=0,s2=0,s3=0,s4=0,s5=0,s6=0,s7=0,s8=0;
#pragma unroll
                for (int w = 0; w < 2; ++w) {
                    u64 A0 = a0[w], A1 = a1[w], B0 = B[j0][w], B1 = B[j1][w];
                    u64 ab  = A0 & B0;
                    u64 ab1 = A0 & B1;
                    u64 cb  = A1 & B0;
                    u64 cb1 = A1 & B1;
                    s0 += __popcll(ab);
                    s1 += __popcll(ab1);
                    s2 += __popcll(ab & B1);
                    s3 += __popcll(cb);
                    s4 += __popcll(cb & A0);
                    s5 += __popcll(cb1);
                    s6 += __popcll(cb1 & A0);
                    s7 += __popcll(cb1 & B0);
                    s8 += __popcll(cb1 & B0 & A0);
                }
                t9[0]=s0; t9[1]=s1; t9[2]=s2; t9[3]=s3; t9[4]=s4;
                t9[5]=s5; t9[6]=s6; t9[7]=s7; t9[8]=s8;
            }
            // pack 3x16b per u64, wave-reduce, post with sentinels
            u64 w0 = (u64)t9[0] | ((u64)t9[1] << 16) | ((u64)t9[2] << 32);
            u64 w1 = (u64)t9[3] | ((u64)t9[4] << 16) | ((u64)t9[5] << 32);
            u64 w2 = (u64)t9[6] | ((u64)t9[7] << 16) | ((u64)t9[8] << 32);
#pragma unroll
            for (int off = 32; off >= 1; off >>= 1) {
                w0 += __shfl_xor(w0, off);
                w1 += __shfl_xor(w1, off);
                w2 += __shfl_xor(w2, off);
            }
            u64* ss = slots + SLOT0 + ((size_t)k * NWG + wg) * 4;
            if (lane == 0) {
                astore64(&ss[0], w0 | (1ull << 63));
                astore64(&ss[1], w1 | (1ull << 63));
                astore64(&ss[2], w2 | (1ull << 63));
            }
            asm volatile("" ::: "memory");
            // gather all 72 step slots
            int T[9];
            {
                const u64* g1 = slots + SLOT0 + ((size_t)k * NWG + lane) * 4;
                const u64* g2 = slots + SLOT0 + ((size_t)k * NWG + 64 + lane) * 4;
                const bool two = (lane < 8);
                u64 x0, x1, x2, y0 = 0, y1 = 0, y2 = 0;
                bool okall;
                do {
                    x0 = aload64(&g1[0]); x1 = aload64(&g1[1]); x2 = aload64(&g1[2]);
                    bool ok = ((x0 & x1 & x2) >> 63) != 0;
                    if (two) {
                        y0 = aload64(&g2[0]); y1 = aload64(&g2[1]); y2 = aload64(&g2[2]);
                        ok &= ((y0 & y1 & y2) >> 63) != 0;
                    }
                    okall = __all(ok);
                } while (!okall);
                u64 q0 = 0, q1 = 0, q2 = 0;   // 3x21b accumulators
#pragma unroll
                for (int f = 0; f < 3; ++f) {
                    q0 += (u64)((x0 >> (f * 16)) & 0xFFFF) << (f * 21);
                    q1 += (u64)((x1 >> (f * 16)) & 0xFFFF) << (f * 21);
                    q2 += (u64)((x2 >> (f * 16)) & 0xFFFF) << (f * 21);
                    if (two) {
                        q0 += (u64)((y0 >> (f * 16)) & 0xFFFF) << (f * 21);
                        q1 += (u64)((y1 >> (f * 16)) & 0xFFFF) << (f * 21);
                        q2 += (u64)((y2 >> (f * 16)) & 0xFFFF) << (f * 21);
                    }
                }
#pragma unroll
                for (int off = 32; off >= 1; off >>= 1) {
                    q0 += __shfl_xor(q0, off);
                    q1 += __shfl_xor(q1, off);
                    q2 += __shfl_xor(q2, off);
                }
#pragma unroll
                for (int f = 0; f < 3; ++f) {
                    T[f]     = (int)((q0 >> (f * 21)) & 0x1FFFFF);
                    T[3 + f] = (int)((q1 >> (f * 21)) & 0x1FFFFF);
                    T[6 + f] = (int)((q2 >> (f * 21)) & 0x1FFFFF);
                }
            }
            // ---- 4 pairs, reference order; fp32 arithmetic replicated ----
            bool a0l = false, b0l = false, b1l = false, a1l = false;
            {   // pair (i0, j0)
                int inter = T[0];
                int uni = pca0 + pcb[j0] - inter;
                float iou = (float)inter / fmaxf((float)uni, 1.0f);
                bool aw = sa0 > sBr[j0];
                if (iou > 0.8f) { if (aw) fbM |= 1u << j0; else fa0 = 1; }
                else if (inter > 0) {
                    if (aw) { pcb[j0] -= inter; b0l = true;
                              B[j0][0] &= ~a0[0]; B[j0][1] &= ~a0[1]; }
                    else    { pca0 -= inter; a0l = true;
                              a0[0] &= ~B[j0][0]; a0[1] &= ~B[j0][1]; }
                }
            }
            {   // pair (i0, j1): exact via basis correction
                int inter = T[1] - (a0l ? T[2] : 0);
                int uni = pca0 + pcb[j1] - inter;
                float iou = (float)inter / fmaxf((float)uni, 1.0f);
                bool aw = sa0 > sBr[j1];
                if (iou > 0.8f) { if (aw) fbM |= 1u << j1; else fa0 = 1; }
                else if (inter > 0) {
                    if (aw) { pcb[j1] -= inter; b1l = true;
                              B[j1][0] &= ~a0[0]; B[j1][1] &= ~a0[1]; }
                    else    { pca0 -= inter;
                              a0[0] &= ~B[j1][0]; a0[1] &= ~B[j1][1]; }
                }
            }
            {   // pair (i1, j0)
                int inter = T[3] - (b0l ? T[4] : 0);
                int uni = pca1 + pcb[j0] - inter;
                float iou = (float)inter / fmaxf((float)uni, 1.0f);
                bool aw = sa1 > sBr[j0];
                if (iou > 0.8f) { if (aw) fbM |= 1u << j0; else fa1 = 1; }
                else if (inter > 0) {
                    if (aw) { pcb[j0] -= inter;
                              B[j0][0] &= ~a1[0]; B[j0][1] &= ~a1[1]; }
                    else    { pca1 -= inter; a1l = true;
                              a1[0] &= ~B[j0][0]; a1[1] &= ~B[j0][1]; }
                }
            }
            {   // pair (i1, j1)
                int termA = T[5] - (b1l ? (T[6] - (a0l ? T[8] : 0)) : 0);
                int inter = termA;
                if (a1l) {
                    int termB = (T[7] - (b0l ? T[8] : 0))
                              - ((b1l && !a0l && !b0l) ? T[8] : 0);
                    inter = termA - termB;
                }
                int uni = pca1 + pcb[j1] - inter;
                float iou = (float)inter / fmaxf((float)uni, 1.0f);
                bool aw = sa1 > sBr[j1];
                if (iou > 0.8f) { if (aw) fbM |= 1u << j1; else fa1 = 1; }
                else if (inter > 0) {
                    if (aw) { pcb[j1] -= inter;
                              B[j1][0] &= ~a1[0]; B[j1][1] &= ~a1[1]; }
                    else    { pca1 -= inter;
                              a1[0] &= ~B[j1][0]; a1[1] &= ~B[j1][1]; }
                }
            }
        }
        // row pair final for this tile: back to LDS; flags accumulate
        ALds[i0][lane] = a0[0]; ALds[i0][64 + lane] = a0[1];
        ALds[i1][lane] = a1[0]; ALds[i1][64 + lane] = a1[1];
        faM |= ((unsigned)fa0 << i0) | ((unsigned)fa1 << i1);
    }

    // ---- writeback final masks + flags; dispatch-end flush publishes ----
    for (int m = 0; m < 16; ++m) {
        A8[(size_t)m * U8PM + base]      = ALds[m][lane];
        A8[(size_t)m * U8PM + base + 64] = ALds[m][64 + lane];
    }
#pragma unroll
    for (int m = 0; m < 16; ++m) {
        B8[(size_t)m * U8PM + base]      = B[m][0];
        B8[(size_t)m * U8PM + base + 64] = B[m][1];
    }
    if (wg == 0 && lane == 0) {
#pragma unroll
        for (int m = 0; m < 16; ++m) {
            meta[16 + m] = (int)((faM >> m) & 1u);
            meta[32 + m] = (int)((fbM >> m) & 1u);
        }
    }
}

// ---------------- kernel 3: expand (coalesced, NT stores) ------------------
__global__ __launch_bounds__(256) void expand_kernel(
    const uint32_t* __restrict__ bitsA, const uint32_t* __restrict__ bitsB,
    const int* __restrict__ meta, float* __restrict__ out)
{
    int g = blockIdx.x * 256 + threadIdx.x;        // float4 index
    int tensor = (g >= F4PT);
    int lg = tensor ? (g - F4PT) : g;
    const uint32_t* bits = tensor ? bitsB : bitsA;
    const int* flags = meta + (tensor ? 32 : 16);
    int m = lg / F4PM;
    bool keep = (flags[m] == 0);
    uint32_t wd = keep ? bits[lg >> 3] : 0u;
    int sh = (lg & 7) * 4;
    vf4 o;
    o.x = ((wd >> (sh + 0)) & 1u) ? 1.0f : 0.0f;
    o.y = ((wd >> (sh + 1)) & 1u) ? 1.0f : 0.0f;
    o.z = ((wd >> (sh + 2)) & 1u) ? 1.0f : 0.0f;
    o.w = ((wd >> (sh + 3)) & 1u) ? 1.0f : 0.0f;
    __builtin_nontemporal_store(o, ((vf4*)out) + g);
    if (g < 2 * NM) {   // keep_a / keep_b tail (flagsA,flagsB contiguous)
        out[(size_t)2 * NM * HW_P + g] = meta[16 + g] ? 0.0f : 1.0f;
    }
}

extern "C" void kernel_launch(void* const* d_in, const int* in_sizes, int n_in,
                              void* d_out, int out_size, void* d_ws, size_t ws_size,
                              hipStream_t stream)
{
    const float* ma = (const float*)d_in[0];
    const float* mb = (const float*)d_in[1];
    const float* sa = (const float*)d_in[2];
    const float* sb = (const float*)d_in[3];
    float* out = (float*)d_out;
    char* ws = (char*)d_ws;

    uint32_t* bitsA = (uint32_t*)(ws);             // 1,179,648 B
    uint32_t* bitsB = (uint32_t*)(ws + 1179648);   // 1,179,648 B
    int* meta       = (int*)(ws + 2359296);        // flags (written by filter)
    u64* slots      = (u64*)(ws + 2363392);        // 154,368 B (zeroed by binarize)

    binarize_kernel<<<18432, 256, 0, stream>>>(ma, mb, bitsA, bitsB,
                                               (uint4*)(ws + 2363392));
    filter_kernel<<<NWG, 64, 0, stream>>>(sa, sb, bitsA, bitsB, meta, slots);
    expand_kernel<<<18432, 256, 0, stream>>>(bitsA, bitsB, meta, out);
}